// Round 4
// baseline (501.685 us; speedup 1.0000x reference)
//
#include <hip/hip_runtime.h>
#include <math.h>

#define BSZ     2
#define LEN     4096
#define DMODEL  1024
#define DINNER  2048
#define DSTATE  128
#define NHEADS  32
#define HDIM    64
#define CONVDIM 2304
#define QC      64
#define NCHUNK  64
#define ROWS    (BSZ*LEN)          // 8192
#define SDIM    (HDIM*DSTATE)      // 8192
#define PB      136                // LDS pitch, natural [row][128+pad]
#define PT      72                 // LDS pitch, transposed [row][64+pad]
#define CGRP    (CONVDIM/8)        // 288 8-channel groups

typedef __attribute__((ext_vector_type(8))) short short8;
typedef __attribute__((ext_vector_type(4))) float f32x4;

__device__ __forceinline__ float silu_(float x){ return x / (1.0f + expf(-x)); }
__device__ __forceinline__ float sigm_(float x){ return 1.0f / (1.0f + expf(-x)); }
__device__ __forceinline__ float bf2f(unsigned short u){
    return __uint_as_float(((unsigned int)u) << 16);
}
__device__ __forceinline__ unsigned short f2bf(float f){
    unsigned int u = __float_as_uint(f);
    u = (u + 0x7fffu + ((u >> 16) & 1u)) >> 16;
    return (unsigned short)u;
}

// XOR swizzle for PT-pitched transposed tiles (chunk_mfma).
__device__ __forceinline__ int swzcol(int row, int col) {
    return ((((col >> 3) ^ (row >> 3)) & 7) << 3) | (col & 7);
}
__device__ __forceinline__ int swzblk(int row, int blk) {
    return (((blk ^ (row >> 3)) & 7) << 3);
}

__device__ __forceinline__ void gload16(const void* g, void* l) {
    __builtin_amdgcn_global_load_lds(
        (const __attribute__((address_space(1))) unsigned int*)g,
        (__attribute__((address_space(3))) unsigned int*)l, 16, 0, 0);
}

// f32 -> bf16 cast, 4 elems/thread
__global__ __launch_bounds__(256) void cast_bf16(const float* __restrict__ src,
                                                 unsigned short* __restrict__ dst,
                                                 int n4) {
    const int i = blockIdx.x * 256 + threadIdx.x;
    if (i >= n4) return;
    const float4 v = *(const float4*)(src + (size_t)i * 4);
    ushort4 o;
    o.x = f2bf(v.x); o.y = f2bf(v.y); o.z = f2bf(v.z); o.w = f2bf(v.w);
    *(ushort4*)(dst + (size_t)i * 4) = o;
}

// ---------------------------------------------------------------------------
// 256x256 8-phase bf16 MFMA GEMM: C[M,N] = A[M,K]*B[N,K]^T, f32 accumulate.
// 2 K-tiles per iteration, one half-tile staged per phase, vmcnt(6) only at
// phases 3/7. Optional split-K (Ks < Kfull) writes C0/C1; caller reduces.
// ---------------------------------------------------------------------------
__device__ __forceinline__ void stage_half(const unsigned short* __restrict__ G,
                                           void* ldsbase, int w, int lane,
                                           size_t rowbase, int lda, int kcol) {
#pragma unroll
    for (int u = 0; u < 2; u++) {
        const int f = w * 128 + u * 64 + lane;      // 16B-chunk index in half-tile
        const int r = f >> 3;                       // row 0..127
        const int cl = (lane & 7) ^ (lane >> 3);    // pre-swizzled source chunk
        gload16(G + rowbase + (size_t)r * lda + kcol + cl * 8,
                (char*)ldsbase + f * 16);
    }
}

#define WAITV(n) asm volatile("s_waitcnt vmcnt(" #n ")" ::: "memory")
#define LGKM0    asm volatile("s_waitcnt lgkmcnt(0)" ::: "memory")
#define BARRIER  do { asm volatile("" ::: "memory"); \
                      __builtin_amdgcn_s_barrier();  \
                      asm volatile("" ::: "memory"); } while (0)

#define READ_A(dst, buf, half)                                                \
    _Pragma("unroll")                                                         \
    for (int fr = 0; fr < 4; fr++) {                                          \
        const int r_ = (w & 1) * 64 + fr * 16 + l16;                          \
        _Pragma("unroll")                                                     \
        for (int s = 0; s < 2; s++)                                           \
            dst[fr][s] = *(const short8*)((const char*)&lds[buf][0][half][0]  \
                + r_ * 128 + (((s * 4 + quad) ^ rx7) << 4));                  \
    }
#define READ_B(dst, buf, half)                                                \
    _Pragma("unroll")                                                         \
    for (int fc = 0; fc < 2; fc++) {                                          \
        const int r_ = (w >> 1) * 32 + fc * 16 + l16;                         \
        _Pragma("unroll")                                                     \
        for (int s = 0; s < 2; s++)                                           \
            dst[fc][s] = *(const short8*)((const char*)&lds[buf][1][half][0]  \
                + r_ * 128 + (((s * 4 + quad) ^ rx7) << 4));                  \
    }
#define MFMA16(g, af, bfv)                                                    \
    __builtin_amdgcn_s_setprio(1);                                            \
    _Pragma("unroll")                                                         \
    for (int s = 0; s < 2; s++)                                               \
        _Pragma("unroll")                                                     \
        for (int fr = 0; fr < 4; fr++)                                        \
            _Pragma("unroll")                                                 \
            for (int fc = 0; fc < 2; fc++)                                    \
                acc[g][fr][fc] = __builtin_amdgcn_mfma_f32_16x16x32_bf16(     \
                    af[fr][s], bfv[fc][s], acc[g][fr][fc], 0, 0, 0);          \
    __builtin_amdgcn_s_setprio(0);

template<bool BF16OUT>
__global__ __launch_bounds__(512, 2) void gemm8p(const unsigned short* __restrict__ A,
                                                 const unsigned short* __restrict__ B,
                                                 void* __restrict__ C0,
                                                 void* __restrict__ C1,
                                                 int N, int Kfull, int Ks,
                                                 int gx, int nwg1) {
    __shared__ unsigned short lds[2][2][2][8192];   // [tile-parity][op][half][128*64]
    const int tid = threadIdx.x;
    const int w = tid >> 6, lane = tid & 63;
    const int quad = lane >> 4, l16 = lane & 15;
    const int rx7 = l16 & 7;

    // bijective XCD swizzle (m204 form)
    const int nwg = gridDim.x;
    const int id = blockIdx.x;
    const int q8 = nwg >> 3, r8 = nwg & 7;
    const int xcd = id & 7, idx = id >> 3;
    const int wg = (xcd < r8 ? xcd * (q8 + 1) : r8 * (q8 + 1) + (xcd - r8) * q8) + idx;
    const int sid = wg / nwg1;
    const int wgl = wg % nwg1;
    const int m0 = (wgl / gx) * 256, n0 = (wgl % gx) * 256;
    const int kbase = sid * Ks;
    void* Cout = sid ? C1 : C0;

    const size_t a0r = (size_t)m0 * Kfull;
    const size_t a1r = (size_t)(m0 + 128) * Kfull;
    const size_t b0r = (size_t)n0 * Kfull;
    const size_t b1r = (size_t)(n0 + 128) * Kfull;

    f32x4 acc[4][4][2];
#pragma unroll
    for (int g = 0; g < 4; g++)
#pragma unroll
        for (int i = 0; i < 4; i++)
#pragma unroll
            for (int j = 0; j < 2; j++) acc[g][i][j] = (f32x4){0.f, 0.f, 0.f, 0.f};

    const int NT = Ks >> 6;            // K-tiles in this split (even; >= 4)
    // prologue: tile0 full (buf0) + tile1 A0,B0,A1 (buf1) = 7 halves
    stage_half(A, &lds[0][0][0][0], w, lane, a0r, Kfull, kbase);
    stage_half(B, &lds[0][1][0][0], w, lane, b0r, Kfull, kbase);
    stage_half(A, &lds[0][0][1][0], w, lane, a1r, Kfull, kbase);
    stage_half(B, &lds[0][1][1][0], w, lane, b1r, Kfull, kbase);
    stage_half(A, &lds[1][0][0][0], w, lane, a0r, Kfull, kbase + 64);
    stage_half(B, &lds[1][1][0][0], w, lane, b0r, Kfull, kbase + 64);
    stage_half(A, &lds[1][0][1][0], w, lane, a1r, Kfull, kbase + 64);
    WAITV(6); BARRIER;

    short8 af0[4][2], af1[4][2], bf0[2][2], bf1[2][2];
    for (int p = 0; p < (NT >> 1) - 1; p++) {
        const int kb1 = kbase + (2 * p + 1) * 64;   // odd tile of THIS pair (its B1)
        const int ka2 = kbase + (2 * p + 2) * 64;   // next even tile
        const int kb2 = kbase + (2 * p + 3) * 64;   // next odd tile
        // ph0: quadrant (A0,B0) of even tile
        READ_A(af0, 0, 0); READ_B(bf0, 0, 0);
        stage_half(B, &lds[1][1][1][0], w, lane, b1r, Kfull, kb1);
        BARRIER; MFMA16(0, af0, bf0); LGKM0; BARRIER;
        // ph1: (A1,B0)
        READ_A(af1, 0, 1);
        stage_half(A, &lds[0][0][0][0], w, lane, a0r, Kfull, ka2);
        BARRIER; MFMA16(1, af1, bf0); LGKM0; BARRIER;
        // ph2: (A0,B1)
        READ_B(bf1, 0, 1);
        stage_half(B, &lds[0][1][0][0], w, lane, b0r, Kfull, ka2);
        BARRIER; MFMA16(2, af0, bf1); LGKM0; BARRIER;
        // ph3: (A1,B1); drain odd tile of this pair (vmcnt 14->6)
        stage_half(A, &lds[0][0][1][0], w, lane, a1r, Kfull, ka2);
        WAITV(6); BARRIER; MFMA16(3, af1, bf1); LGKM0; BARRIER;
        // ph4: (A0,B0) of odd tile
        READ_A(af0, 1, 0); READ_B(bf0, 1, 0);
        stage_half(B, &lds[0][1][1][0], w, lane, b1r, Kfull, ka2);
        BARRIER; MFMA16(0, af0, bf0); LGKM0; BARRIER;
        // ph5: (A1,B0)
        READ_A(af1, 1, 1);
        stage_half(A, &lds[1][0][0][0], w, lane, a0r, Kfull, kb2);
        BARRIER; MFMA16(1, af1, bf0); LGKM0; BARRIER;
        // ph6: (A0,B1)
        READ_B(bf1, 1, 1);
        stage_half(B, &lds[1][1][0][0], w, lane, b0r, Kfull, kb2);
        BARRIER; MFMA16(2, af0, bf1); LGKM0; BARRIER;
        // ph7: (A1,B1); drain next even tile
        stage_half(A, &lds[1][0][1][0], w, lane, a1r, Kfull, kb2);
        WAITV(6); BARRIER; MFMA16(3, af1, bf1); LGKM0; BARRIER;
    }
    // epilogue pair: tiles NT-2 (buf0, fully landed), NT-1 (buf1; B1 staged here)
    READ_A(af0, 0, 0); READ_B(bf0, 0, 0);
    stage_half(B, &lds[1][1][1][0], w, lane, b1r, Kfull, kbase + (NT - 1) * 64);
    MFMA16(0, af0, bf0);
    READ_A(af1, 0, 1);
    MFMA16(1, af1, bf0);
    READ_B(bf1, 0, 1);
    MFMA16(2, af0, bf1);
    MFMA16(3, af1, bf1);
    WAITV(0); LGKM0; BARRIER;
    READ_A(af0, 1, 0); READ_B(bf0, 1, 0);
    MFMA16(0, af0, bf0);
    READ_A(af1, 1, 1);
    MFMA16(1, af1, bf0);
    READ_B(bf1, 1, 1);
    MFMA16(2, af0, bf1);
    MFMA16(3, af1, bf1);

    // C write
#pragma unroll
    for (int g = 0; g < 4; g++) {
        const int qm = g & 1, qn = g >> 1;
        const int mb = m0 + qm * 128 + (w & 1) * 64;
        const int nb2 = n0 + qn * 128 + (w >> 1) * 32;
#pragma unroll
        for (int fr = 0; fr < 4; fr++)
#pragma unroll
            for (int fc = 0; fc < 2; fc++) {
                const int n = nb2 + fc * 16 + l16;
#pragma unroll
                for (int rr = 0; rr < 4; rr++) {
                    const int m = mb + fr * 16 + quad * 4 + rr;
                    if (BF16OUT)
                        ((unsigned short*)Cout)[(size_t)m * N + n] = f2bf(acc[g][fr][fc][rr]);
                    else
                        ((float*)Cout)[(size_t)m * N + n] = acc[g][fr][fc][rr];
                }
            }
    }
}

// ---------------------------------------------------------------------------
// Skinny dt projection: BM=32, grid 256. Waves split K (256 each) with
// per-wave double-buffered global_load_lds (no barriers in K-loop); f32
// LDS reduce across waves, fused bias+sigmoid epilogue.
// ---------------------------------------------------------------------------
__global__ __launch_bounds__(256) void dtproj_mfma(const unsigned short* __restrict__ A,
                                                   const unsigned short* __restrict__ W,
                                                   const float* __restrict__ bias,
                                                   float* __restrict__ dtb,
                                                   int K) {
    __shared__ unsigned short As[4][2][32 * 32];
    __shared__ unsigned short Ws[4][2][32 * 32];
    __shared__ float red[4][32][32];
    const int tid = threadIdx.x;
    const int w = tid >> 6, lane = tid & 63;
    const int quad = lane >> 4, l16 = lane & 15;
    const int m0 = blockIdx.x * 32;
    const int kbeg = w * (1024 / 4);

    f32x4 acc[2][2];
#pragma unroll
    for (int i = 0; i < 2; i++)
#pragma unroll
        for (int j = 0; j < 2; j++) acc[i][j] = (f32x4){0.f, 0.f, 0.f, 0.f};

#define DTSTAGE(buf, kt)                                                      \
    _Pragma("unroll")                                                         \
    for (int u = 0; u < 2; u++) {                                             \
        const int f = u * 64 + lane;                                          \
        const int row = f >> 2, ke = (f & 3) * 8;                             \
        gload16(A + (size_t)(m0 + row) * K + (kt) + ke,                       \
                (char*)&As[w][buf][0] + f * 16);                              \
        gload16(W + (size_t)row * K + (kt) + ke,                              \
                (char*)&Ws[w][buf][0] + f * 16);                              \
    }

    DTSTAGE(0, kbeg);
    int buf = 0;
    for (int it = 0; it < 8; it++) {
        if (it < 7) { DTSTAGE(buf ^ 1, kbeg + (it + 1) * 32); WAITV(4); }
        else        { WAITV(0); }
        short8 af[2], bfr[2];
#pragma unroll
        for (int i = 0; i < 2; i++)
            af[i] = *(const short8*)((const char*)&As[w][buf][0] + (i * 16 + l16) * 64 + quad * 16);
#pragma unroll
        for (int j = 0; j < 2; j++)
            bfr[j] = *(const short8*)((const char*)&Ws[w][buf][0] + (j * 16 + l16) * 64 + quad * 16);
#pragma unroll
        for (int i = 0; i < 2; i++)
#pragma unroll
            for (int j = 0; j < 2; j++)
                acc[i][j] = __builtin_amdgcn_mfma_f32_16x16x32_bf16(
                    af[i], bfr[j], acc[i][j], 0, 0, 0);
        buf ^= 1;
    }
#pragma unroll
    for (int i = 0; i < 2; i++)
#pragma unroll
        for (int j = 0; j < 2; j++)
#pragma unroll
            for (int r = 0; r < 4; r++)
                red[w][i * 16 + quad * 4 + r][j * 16 + l16] = acc[i][j][r];
    __syncthreads();
#pragma unroll
    for (int e = 0; e < 4; e++) {
        const int o = tid + e * 256;
        const int m = o >> 5, hh = o & 31;
        const float v = red[0][m][hh] + red[1][m][hh] + red[2][m][hh] + red[3][m][hh];
        dtb[(size_t)m0 * NHEADS + o] = 0.001f + 0.099f * sigm_(v + bias[hh]);
    }
}

// ---------------------------------------------------------------------------
// Depthwise causal conv (K=4) + bias + SiLU, bf16 in/out.
// ---------------------------------------------------------------------------
__global__ __launch_bounds__(256) void conv_silu_w(const unsigned short* __restrict__ xbc,
                                                   const float* __restrict__ cw,
                                                   const float* __restrict__ cb,
                                                   unsigned short* __restrict__ xssm,
                                                   unsigned short* __restrict__ Bb,
                                                   unsigned short* __restrict__ Cb) {
    const int idx = blockIdx.x * 256 + threadIdx.x;   // < (ROWS/4)*CGRP
    const int g = idx % CGRP;
    const int rowblk = idx / CGRP;
    const long row0 = (long)rowblk * 4;
    const int lbase = (int)(row0 & (LEN - 1));        // position within sequence
    const int j0 = g * 8;

    float4 wv[8];
    float cbv[8];
#pragma unroll
    for (int e = 0; e < 8; e++) {
        wv[e] = *(const float4*)(cw + (size_t)(j0 + e) * 4);
        cbv[e] = cb[j0 + e];
    }

    short8 win[4];
    const short8 zero8 = (short8){0, 0, 0, 0, 0, 0, 0, 0};
#pragma unroll
    for (int t = 0; t < 3; t++) {
        const int lr = lbase - 3 + t;
        win[t] = (lr >= 0) ? *(const short8*)(xbc + (row0 - 3 + t) * CONVDIM + j0)
                           : zero8;
    }
#pragma unroll
    for (int i = 0; i < 4; i++) {
        win[3] = *(const short8*)(xbc + (row0 + i) * CONVDIM + j0);
        short8 o;
#pragma unroll
        for (int e = 0; e < 8; e++) {
            float acc = cbv[e];
            acc += bf2f((unsigned short)win[0][e]) * wv[e].x;
            acc += bf2f((unsigned short)win[1][e]) * wv[e].y;
            acc += bf2f((unsigned short)win[2][e]) * wv[e].z;
            acc += bf2f((unsigned short)win[3][e]) * wv[e].w;
            o[e] = (short)f2bf(silu_(acc));
        }
        const long row = row0 + i;
        if (j0 < DINNER)
            *(short8*)(xssm + row * DINNER + j0) = o;
        else if (j0 < DINNER + DSTATE)
            *(short8*)(Bb + row * DSTATE + (j0 - DINNER)) = o;
        else
            *(short8*)(Cb + row * DSTATE + (j0 - DINNER - DSTATE)) = o;
        win[0] = win[1]; win[1] = win[2]; win[2] = win[3];
    }
}

__global__ __launch_bounds__(64) void acum_kernel(const float* __restrict__ dtb,
                                                  const float* __restrict__ A_log,
                                                  float* __restrict__ Acum) {
    const int c = blockIdx.x, h = blockIdx.y, b = blockIdx.z;
    const int q = threadIdx.x;
    const float Av = -expf(A_log[h]);
    float v = dtb[((size_t)b * LEN + c * QC + q) * NHEADS + h] * Av;
#pragma unroll
    for (int off = 1; off < 64; off <<= 1) {
        const float n = __shfl_up(v, off, 64);
        if (q >= off) v += n;
    }
    Acum[(((size_t)b * NHEADS + h) * NCHUNK + c) * QC + q] = v;
}

// ---------------------------------------------------------------------------
// MFMA chunk kernel (PT tiles XOR-swizzled).
// ---------------------------------------------------------------------------
__global__ __launch_bounds__(256) void chunk_mfma(const unsigned short* __restrict__ xssm,
                                                  const unsigned short* __restrict__ Bb,
                                                  const unsigned short* __restrict__ Cb,
                                                  const float* __restrict__ dtb,
                                                  const float* __restrict__ Acum,
                                                  const float* __restrict__ Dskip,
                                                  unsigned short* __restrict__ Y,
                                                  unsigned short* __restrict__ states) {
    const int c = blockIdx.x, h = blockIdx.y, b = blockIdx.z;
    const int tid = threadIdx.x;
    const int wave = tid >> 6, lane = tid & 63;
    const int quad = lane >> 4, l16 = lane & 15;

    __shared__ __attribute__((aligned(16))) unsigned short Bsh[8704];
    __shared__ __attribute__((aligned(16))) unsigned short Csh[9216];
    __shared__ __attribute__((aligned(16))) unsigned short xTs[4608];
    __shared__ float ac[QC], dts[QC], decs[QC];

    const size_t rowbase = (size_t)b * LEN + c * QC;
    if (tid < QC) {
        ac[tid]  = Acum[(((size_t)b * NHEADS + h) * NCHUNK + c) * QC + tid];
        dts[tid] = dtb[(rowbase + tid) * NHEADS + h];
    }
#pragma unroll
    for (int u = 0; u < 4; u++) {
        const int vi = u * 256 + tid;
        const int s = vi >> 4, n0 = (vi & 15) * 8;
        *(short8*)&Bsh[s * PB + n0] = *(const short8*)(Bb + (rowbase + s) * DSTATE + n0);
        *(short8*)&Csh[s * PB + n0] = *(const short8*)(Cb + (rowbase + s) * DSTATE + n0);
    }
#pragma unroll
    for (int u = 0; u < 2; u++) {
        const int vi = u * 256 + tid;
        const int q = vi >> 3, p0 = (vi & 7) * 8;
        const short8 v = *(const short8*)(xssm + (rowbase + q) * DINNER + h * HDIM + p0);
#pragma unroll
        for (int j = 0; j < 8; j++) {
            const int p = p0 + j;
            xTs[p * PT + swzcol(p, q)] = (unsigned short)v[j];
        }
    }
    __syncthreads();
    if (tid < QC) decs[tid] = expf(ac[QC - 1] - ac[tid]) * dts[tid];

    // Phase 1: S = C . B^T   (PB natural layout)
    f32x4 S[4];
#pragma unroll
    for (int j = 0; j < 4; j++) S[j] = (f32x4){0.f, 0.f, 0.f, 0.f};
    const int qa = wave * 16 + l16;
#pragma unroll
    for (int ks = 0; ks < 4; ks++) {
        const short8 a = *(const short8*)&Csh[qa * PB + ks * 32 + quad * 8];
#pragma unroll
        for (int j = 0; j < 4; j++) {
            const short8 bb = *(const short8*)&Bsh[(j * 16 + l16) * PB + ks * 32 + quad * 8];
            S[j] = __builtin_amdgcn_mfma_f32_16x16x32_bf16(a, bb, S[j], 0, 0, 0);
        }
    }
    unsigned short slv[4][4];
#pragma unroll
    for (int j = 0; j < 4; j++)
#pragma unroll
        for (int r = 0; r < 4; r++) {
            const int q = wave * 16 + quad * 4 + r, s = j * 16 + l16;
            const float v = (s <= q) ? S[j][r] * expf(ac[q] - ac[s]) * dts[s] : 0.f;
            slv[j][r] = f2bf(v);
        }
    __syncthreads();

    // B'[n][s] = B[s][n]*decs[s], written swizzled into Csh (PT pitch).
    {
        const int sin = lane & 7;
        const int ng  = lane >> 3;
#pragma unroll
        for (int so = 0; so < 2; so++) {
            const int s = (wave * 2 + so) * 8 + sin;
            const float d = decs[s];
            const int cbk = s >> 3;
#pragma unroll
            for (int nh = 0; nh < 2; nh++) {
                const int noct = ng + 8 * nh;
                const int colphys = (((cbk ^ noct) & 7) << 3) | (s & 7);
#pragma unroll
                for (int j = 0; j < 8; j++) {
                    const int n = noct * 8 + ((j + sin) & 7);
                    Csh[n * PT + colphys] = f2bf(bf2f(Bsh[s * PB + n]) * d);
                }
            }
        }
    }
    __syncthreads();

#pragma unroll
    for (int j = 0; j < 4; j++)
#pragma unroll
        for (int r = 0; r < 4; r++) {
            const int row = wave * 16 + quad * 4 + r;
            const int col = j * 16 + l16;
            Bsh[row * PT + swzcol(row, col)] = slv[j][r];
        }
    __syncthreads();

    // Phase 2: Yd = SL . x
    f32x4 yd[4];
#pragma unroll
    for (int j = 0; j < 4; j++) yd[j] = (f32x4){0.f, 0.f, 0.f, 0.f};
#pragma unroll
    for (int ks = 0; ks < 2; ks++) {
        const int blk = ks * 4 + quad;
        const short8 a = *(const short8*)&Bsh[qa * PT + swzblk(qa, blk)];
#pragma unroll
        for (int j = 0; j < 4; j++) {
            const int row = j * 16 + l16;
            const short8 xb = *(const short8*)&xTs[row * PT + swzblk(row, blk)];
            yd[j] = __builtin_amdgcn_mfma_f32_16x16x32_bf16(a, xb, yd[j], 0, 0, 0);
        }
    }
    const float Dh = Dskip[h];
#pragma unroll
    for (int j = 0; j < 4; j++)
#pragma unroll
        for (int r = 0; r < 4; r++) {
            const int q = wave * 16 + quad * 4 + r, p = j * 16 + l16;
            const float v = yd[j][r] + Dh * bf2f(xTs[p * PT + swzcol(p, q)]);
            Y[(rowbase + q) * DINNER + h * HDIM + p] = f2bf(v);
        }

    // Phase 3: states = xT . B'
    f32x4 st[8];
#pragma unroll
    for (int j = 0; j < 8; j++) st[j] = (f32x4){0.f, 0.f, 0.f, 0.f};
#pragma unroll
    for (int ks = 0; ks < 2; ks++) {
        const int blk = ks * 4 + quad;
        const short8 a = *(const short8*)&xTs[qa * PT + swzblk(qa, blk)];
#pragma unroll
        for (int j = 0; j < 8; j++) {
            const int row = j * 16 + l16;
            const short8 bb = *(const short8*)&Csh[row * PT + swzblk(row, blk)];
            st[j] = __builtin_amdgcn_mfma_f32_16x16x32_bf16(a, bb, st[j], 0, 0, 0);
        }
    }
    const size_t sbase = (((size_t)b * NHEADS + h) * NCHUNK + c) * SDIM;
#pragma unroll
    for (int j = 0; j < 8; j++)
#pragma unroll
        for (int r = 0; r < 4; r++) {
            const int p = wave * 16 + quad * 4 + r, n = j * 16 + l16;
            states[sbase + (size_t)p * DSTATE + n] = f2bf(st[j][r]);
        }
}

// ---------------------------------------------------------------------------
// Fused inter-chunk scan + Yo: carry kept in registers in MFMA-B-fragment
// layout (lane(l16,quad): prev[p=l16][n=quad*8+32s+j]); prevs never stored.
// Grid (4 p-slices, 32 h, 2 b) = 256 blocks, 4 waves (one per 16-q band),
// depth-4 register prefetch of C/states. Sequential over 64 chunks.
// ---------------------------------------------------------------------------
__global__ __launch_bounds__(256) void scanyo_mfma(const unsigned short* __restrict__ Cb,
                                                   const unsigned short* __restrict__ states,
                                                   const float* __restrict__ Acum,
                                                   unsigned short* __restrict__ Y) {
    const int pb = blockIdx.x;            // p-slice 0..3
    const int h = blockIdx.y, b = blockIdx.z;
    const int tid = threadIdx.x;
    const int w = tid >> 6, lane = tid & 63;
    const int quad = lane >> 4, l16 = lane & 15;
    const size_t bh = (size_t)b * NHEADS + h;
    const float* Ac = Acum + bh * NCHUNK * QC;
    const size_t rowb0 = (size_t)b * LEN;

    float carry[4][8];
#pragma unroll
    for (int s = 0; s < 4; s++)
#pragma unroll
        for (int j = 0; j < 8; j++) carry[s][j] = 0.f;

    const unsigned short* stp = states + bh * NCHUNK * SDIM
                              + (size_t)(pb * 16 + l16) * DSTATE + quad * 8;
    const unsigned short* cp = Cb + (rowb0 + (size_t)w * 16 + l16) * DSTATE + quad * 8;

    short8 cR[4][4], sR[4][4];
#define LOADCH(ri, c)                                                          \
    _Pragma("unroll")                                                          \
    for (int s = 0; s < 4; s++) {                                              \
        cR[ri][s] = *(const short8*)(cp + (size_t)(c) * (QC * DSTATE) + s * 32); \
        sR[ri][s] = *(const short8*)(stp + (size_t)(c) * SDIM + s * 32);       \
    }
#define PROC(ri, c)                                                            \
    {                                                                          \
        const float dec_c = expf(Ac[(c) * QC + (QC - 1)]);                     \
        float eqv[4];                                                          \
        _Pragma("unroll")                                                      \
        for (int r = 0; r < 4; r++)                                            \
            eqv[r] = expf(Ac[(c) * QC + w * 16 + quad * 4 + r]);               \
        short8 pv[4];                                                          \
        _Pragma("unroll")                                                      \
        for (int s = 0; s < 4; s++)                                            \
            _Pragma("unroll")                                                  \
            for (int j = 0; j < 8; j++)                                        \
                pv[s][j] = (short)f2bf(carry[s][j]);                           \
        f32x4 acc = (f32x4){0.f, 0.f, 0.f, 0.f};                               \
        _Pragma("unroll")                                                      \
        for (int s = 0; s < 4; s++)                                            \
            acc = __builtin_amdgcn_mfma_f32_16x16x32_bf16(cR[ri][s], pv[s], acc, 0, 0, 0); \
        _Pragma("unroll")                                                      \
        for (int s = 0; s < 4; s++)                                            \
            _Pragma("unroll")                                                  \
            for (int j = 0; j < 8; j++)                                        \
                carry[s][j] = dec_c * carry[s][j] + bf2f((unsigned short)sR[ri][s][j]); \
        _Pragma("unroll")                                                      \
        for (int r = 0; r < 4; r++) {                                          \
            const size_t off = (rowb0 + (size_t)(c) * QC + w * 16 + quad * 4 + r) * DINNER \
                             + h * HDIM + pb * 16 + l16;                       \
            Y[off] = f2bf(bf2f(Y[off]) + eqv[r] * acc[r]);                     \
        }                                                                      \
    }

    LOADCH(0, 0); LOADCH(1, 1); LOADCH(2, 2); LOADCH(3, 3);
    for (int c = 0; c < NCHUNK; c += 4) {
        PROC(0, c);
        if (c + 4 < NCHUNK) LOADCH(0, c + 4);
        PROC(1, c + 1);
        if (c + 5 < NCHUNK) LOADCH(1, c + 5);
        PROC(2, c + 2);
        if (c + 6 < NCHUNK) LOADCH(2, c + 6);
        PROC(3, c + 3);
        if (c + 7 < NCHUNK) LOADCH(3, c + 7);
    }
#undef LOADCH
#undef PROC
}

// y = Y * silu(z); RMS-norm; write bf16 for GEMM2  (all bf16 I/O)
__global__ __launch_bounds__(256) void gate_rms(const unsigned short* __restrict__ Y,
                                                const unsigned short* __restrict__ zbf,
                                                const float* __restrict__ nw,
                                                unsigned short* __restrict__ ybf) {
    const int r = blockIdx.x, tid = threadIdx.x;
    float4 yv[2];
    float ss = 0.f;
#pragma unroll
    for (int u = 0; u < 2; u++) {
        const int col = u * 1024 + tid * 4;
        const ushort4 y4 = *(const ushort4*)(Y + (size_t)r * DINNER + col);
        const ushort4 z4 = *(const ushort4*)(zbf + (size_t)r * DINNER + col);
        float4 y;
        y.x = bf2f(y4.x) * silu_(bf2f(z4.x)); y.y = bf2f(y4.y) * silu_(bf2f(z4.y));
        y.z = bf2f(y4.z) * silu_(bf2f(z4.z)); y.w = bf2f(y4.w) * silu_(bf2f(z4.w));
        yv[u] = y;
        ss += y.x * y.x + y.y * y.y + y.z * y.z + y.w * y.w;
    }
#pragma unroll
    for (int off = 32; off; off >>= 1) ss += __shfl_xor(ss, off, 64);
    __shared__ float red[4];
    if ((tid & 63) == 0) red[tid >> 6] = ss;
    __syncthreads();
    ss = red[0] + red[1] + red[2] + red[3];
    const float scale = rsqrtf(ss / (float)DINNER + 1e-5f);
#pragma unroll
    for (int u = 0; u < 2; u++) {
        const int col = u * 1024 + tid * 4;
        const float4 w4 = *(const float4*)(nw + col);
        ushort4 o;
        o.x = f2bf(yv[u].x * scale * w4.x); o.y = f2bf(yv[u].y * scale * w4.y);
        o.z = f2bf(yv[u].z * scale * w4.z); o.w = f2bf(yv[u].w * scale * w4.w);
        *(ushort4*)(ybf + (size_t)r * DINNER + col) = o;
    }
}

// LayerNorm over D + residual. outb + part are summed (split-K partials).
__global__ __launch_bounds__(256) void ln_res(const float* __restrict__ outb,
                                              const float* __restrict__ part,
                                              const float* __restrict__ x,
                                              const float* __restrict__ lw,
                                              const float* __restrict__ lb,
                                              float* __restrict__ out) {
    const int r = blockIdx.x, tid = threadIdx.x;
    const int col = tid * 4;
    float4 v = *(const float4*)(outb + (size_t)r * DMODEL + col);
    const float4 pv = *(const float4*)(part + (size_t)r * DMODEL + col);
    v.x += pv.x; v.y += pv.y; v.z += pv.z; v.w += pv.w;
    float s = v.x + v.y + v.z + v.w;
    float s2 = v.x * v.x + v.y * v.y + v.z * v.z + v.w * v.w;
#pragma unroll
    for (int off = 32; off; off >>= 1) {
        s += __shfl_xor(s, off, 64);
        s2 += __shfl_xor(s2, off, 64);
    }
    __shared__ float rs[4], rs2[4];
    if ((tid & 63) == 0) { rs[tid >> 6] = s; rs2[tid >> 6] = s2; }
    __syncthreads();
    s = rs[0] + rs[1] + rs[2] + rs[3];
    s2 = rs2[0] + rs2[1] + rs2[2] + rs2[3];
    const float mu = s / (float)DMODEL;
    const float var = s2 / (float)DMODEL - mu * mu;
    const float inv = rsqrtf(var + 1e-5f);
    const float4 xw = *(const float4*)(x + (size_t)r * DMODEL + col);
    const float4 w4 = *(const float4*)(lw + col);
    const float4 b4 = *(const float4*)(lb + col);
    float4 o;
    o.x = xw.x + (v.x - mu) * inv * w4.x + b4.x;
    o.y = xw.y + (v.y - mu) * inv * w4.y + b4.y;
    o.z = xw.z + (v.z - mu) * inv * w4.z + b4.z;
    o.w = xw.w + (v.w - mu) * inv * w4.w + b4.w;
    *(float4*)(out + (size_t)r * DMODEL + col) = o;
}

extern "C" void kernel_launch(void* const* d_in, const int* in_sizes, int n_in,
                              void* d_out, int out_size, void* d_ws, size_t ws_size,
                              hipStream_t stream) {
    const float* x          = (const float*)d_in[0];
    const float* in_proj_w  = (const float*)d_in[1];
    const float* conv_w     = (const float*)d_in[2];
    const float* conv_b     = (const float*)d_in[3];
    const float* dt_bias    = (const float*)d_in[4];
    const float* A_log      = (const float*)d_in[5];
    const float* D_skip     = (const float*)d_in[6];
    const float* norm_w     = (const float*)d_in[7];
    const float* out_proj_w = (const float*)d_in[8];
    const float* ln_w       = (const float*)d_in[9];
    const float* ln_b       = (const float*)d_in[10];
    float* out = (float*)d_out;
    float* ws = (float*)d_ws;

    // Workspace layout (float units). ~243 MB.
    size_t off = 0;
    unsigned short* zbf     = (unsigned short*)(ws + off); off += (size_t)ROWS * DINNER / 2;
    unsigned short* xssm_bf = (unsigned short*)(ws + off); off += (size_t)ROWS * DINNER / 2;
    unsigned short* uni     = (unsigned short*)(ws + off); off += (size_t)ROWS * CONVDIM / 2;
    unsigned short* Bb_bf   = (unsigned short*)(ws + off); off += (size_t)ROWS * DSTATE / 2;
    unsigned short* Cb_bf   = (unsigned short*)(ws + off); off += (size_t)ROWS * DSTATE / 2;
    float* dtb   = ws + off; off += (size_t)ROWS * NHEADS;
    float* Acum  = ws + off; off += (size_t)BSZ * NHEADS * NCHUNK * QC;
    unsigned short* x_bf  = (unsigned short*)(ws + off); off += (size_t)ROWS * DMODEL / 2;
    unsigned short* wi_bf = (unsigned short*)(ws + off); off += (size_t)4384 * DMODEL / 2;
    unsigned short* wo_bf = (unsigned short*)(ws + off); off += (size_t)DMODEL * DINNER / 2;
    unsigned short* states = (unsigned short*)(ws + off); off += (size_t)BSZ * NHEADS * NCHUNK * SDIM / 2;
    float* part = ws + off; off += (size_t)ROWS * DMODEL;   // split-K partial (f32)
    const size_t need_bytes = off * sizeof(float);
    if (ws_size < need_bytes) return;   // fail cleanly instead of faulting

    unsigned short* xbc_bf = uni;        // dies after conv
    unsigned short* Ybf    = uni;        // chunk output overlays dead xbc
    unsigned short* ybf    = xssm_bf;    // gate output overlays dead xssm

    // Casts
    cast_bf16<<<(ROWS * DMODEL / 4 + 255) / 256, 256, 0, stream>>>(x, x_bf, ROWS * DMODEL / 4);
    cast_bf16<<<(4384 * DMODEL / 4 + 255) / 256, 256, 0, stream>>>(in_proj_w, wi_bf, 4384 * DMODEL / 4);
    cast_bf16<<<(DMODEL * DINNER / 4 + 255) / 256, 256, 0, stream>>>(out_proj_w, wo_bf, DMODEL * DINNER / 4);

    // In-projection (256^2 8-phase bf16 MFMA): z, xBC; dt via skinny MFMA
    gemm8p<true><<<(ROWS / 256) * (DINNER / 256), 512, 0, stream>>>(
        x_bf, wi_bf, zbf, nullptr, DINNER, DMODEL, DMODEL,
        DINNER / 256, (ROWS / 256) * (DINNER / 256));
    gemm8p<true><<<(ROWS / 256) * (CONVDIM / 256), 512, 0, stream>>>(
        x_bf, wi_bf + (size_t)DINNER * DMODEL, xbc_bf, nullptr, CONVDIM, DMODEL, DMODEL,
        CONVDIM / 256, (ROWS / 256) * (CONVDIM / 256));
    dtproj_mfma<<<ROWS / 32, 256, 0, stream>>>(
        x_bf, wi_bf + (size_t)(DINNER + CONVDIM) * DMODEL, dt_bias, dtb, DMODEL);

    conv_silu_w<<<(ROWS / 4) * CGRP / 256, 256, 0, stream>>>(
        xbc_bf, conv_w, conv_b, xssm_bf, Bb_bf, Cb_bf);
    acum_kernel<<<dim3(NCHUNK, NHEADS, BSZ), 64, 0, stream>>>(dtb, A_log, Acum);
    chunk_mfma<<<dim3(NCHUNK, NHEADS, BSZ), 256, 0, stream>>>(
        xssm_bf, Bb_bf, Cb_bf, dtb, Acum, D_skip, Ybf, states);
    scanyo_mfma<<<dim3(4, NHEADS, BSZ), 256, 0, stream>>>(
        Cb_bf, states, Acum, Ybf);
    gate_rms<<<ROWS, 256, 0, stream>>>(Ybf, zbf, norm_w, ybf);

    // Out-projection: split-K=2 (K=2048 -> 2x1024), grid 256, one dispatch.
    gemm8p<false><<<2 * (ROWS / 256) * (DMODEL / 256), 512, 0, stream>>>(
        ybf, wo_bf, out, part, DMODEL, DINNER, DINNER / 2,
        DMODEL / 256, (ROWS / 256) * (DMODEL / 256));
    ln_res<<<ROWS, 256, 0, stream>>>(out, part, x, ln_w, ln_b, out);
}

// Round 5
// 402.697 us; speedup vs baseline: 1.2458x; 1.2458x over previous
//
#include <hip/hip_runtime.h>
#include <math.h>

#define BSZ     2
#define LEN     4096
#define DMODEL  1024
#define DINNER  2048
#define DSTATE  128
#define NHEADS  32
#define HDIM    64
#define CONVDIM 2304
#define QC      64
#define NCHUNK  64
#define ROWS    (BSZ*LEN)          // 8192
#define SDIM    (HDIM*DSTATE)      // 8192
#define PB      136                // LDS pitch, natural [row][128+pad]
#define PT      72                 // LDS pitch, transposed [row][64+pad]
#define CGRP    (CONVDIM/8)        // 288 8-channel groups

typedef __attribute__((ext_vector_type(8))) short short8;
typedef __attribute__((ext_vector_type(4))) float f32x4;

__device__ __forceinline__ float silu_(float x){ return x / (1.0f + expf(-x)); }
__device__ __forceinline__ float sigm_(float x){ return 1.0f / (1.0f + expf(-x)); }
__device__ __forceinline__ float bf2f(unsigned short u){
    return __uint_as_float(((unsigned int)u) << 16);
}
__device__ __forceinline__ unsigned short f2bf(float f){
    unsigned int u = __float_as_uint(f);
    u = (u + 0x7fffu + ((u >> 16) & 1u)) >> 16;
    return (unsigned short)u;
}

// XOR swizzle for PT-pitched transposed tiles (chunk_mfma).
__device__ __forceinline__ int swzcol(int row, int col) {
    return ((((col >> 3) ^ (row >> 3)) & 7) << 3) | (col & 7);
}
__device__ __forceinline__ int swzblk(int row, int blk) {
    return (((blk ^ (row >> 3)) & 7) << 3);
}

__device__ __forceinline__ void gload16(const void* g, void* l) {
    __builtin_amdgcn_global_load_lds(
        (const __attribute__((address_space(1))) unsigned int*)g,
        (__attribute__((address_space(3))) unsigned int*)l, 16, 0, 0);
}

__device__ __forceinline__ void cast4(const float* __restrict__ src,
                                      unsigned short* __restrict__ dst, int i) {
    const float4 v = *(const float4*)(src + (size_t)i * 4);
    ushort4 o;
    o.x = f2bf(v.x); o.y = f2bf(v.y); o.z = f2bf(v.z); o.w = f2bf(v.w);
    *(ushort4*)(dst + (size_t)i * 4) = o;
}

// fused f32->bf16 cast of three arrays in one dispatch
__global__ __launch_bounds__(256) void cast3(const float* __restrict__ s0, unsigned short* __restrict__ d0, int n0,
                                             const float* __restrict__ s1, unsigned short* __restrict__ d1, int n1,
                                             const float* __restrict__ s2, unsigned short* __restrict__ d2, int n2) {
    int i = blockIdx.x * 256 + threadIdx.x;
    if (i < n0) { cast4(s0, d0, i); return; }
    i -= n0;
    if (i < n1) { cast4(s1, d1, i); return; }
    i -= n1;
    if (i < n2) cast4(s2, d2, i);
}

// ---------------------------------------------------------------------------
// 256x256 8-phase bf16 MFMA GEMM: C[M,N] = A[M,K]*B[N,K]^T, f32 accumulate.
// 2 K-tiles per iteration, one half-tile staged per phase, vmcnt(6) only at
// phases 3/7. Optional split-K (Ks < Kfull) writes C0/C1; caller reduces.
// ---------------------------------------------------------------------------
__device__ __forceinline__ void stage_half(const unsigned short* __restrict__ G,
                                           void* ldsbase, int w, int lane,
                                           size_t rowbase, int lda, int kcol) {
#pragma unroll
    for (int u = 0; u < 2; u++) {
        const int f = w * 128 + u * 64 + lane;      // 16B-chunk index in half-tile
        const int r = f >> 3;                       // row 0..127
        const int cl = (lane & 7) ^ (lane >> 3);    // pre-swizzled source chunk
        gload16(G + rowbase + (size_t)r * lda + kcol + cl * 8,
                (char*)ldsbase + f * 16);
    }
}

#define WAITV(n) asm volatile("s_waitcnt vmcnt(" #n ")" ::: "memory")
#define LGKM0    asm volatile("s_waitcnt lgkmcnt(0)" ::: "memory")
#define BARRIER  do { asm volatile("" ::: "memory"); \
                      __builtin_amdgcn_s_barrier();  \
                      asm volatile("" ::: "memory"); } while (0)

#define READ_A(dst, buf, half)                                                \
    _Pragma("unroll")                                                         \
    for (int fr = 0; fr < 4; fr++) {                                          \
        const int r_ = (w & 1) * 64 + fr * 16 + l16;                          \
        _Pragma("unroll")                                                     \
        for (int s = 0; s < 2; s++)                                           \
            dst[fr][s] = *(const short8*)((const char*)&lds[buf][0][half][0]  \
                + r_ * 128 + (((s * 4 + quad) ^ rx7) << 4));                  \
    }
#define READ_B(dst, buf, half)                                                \
    _Pragma("unroll")                                                         \
    for (int fc = 0; fc < 2; fc++) {                                          \
        const int r_ = (w >> 1) * 32 + fc * 16 + l16;                         \
        _Pragma("unroll")                                                     \
        for (int s = 0; s < 2; s++)                                           \
            dst[fc][s] = *(const short8*)((const char*)&lds[buf][1][half][0]  \
                + r_ * 128 + (((s * 4 + quad) ^ rx7) << 4));                  \
    }
#define MFMA16(g, af, bfv)                                                    \
    __builtin_amdgcn_s_setprio(1);                                            \
    _Pragma("unroll")                                                         \
    for (int s = 0; s < 2; s++)                                               \
        _Pragma("unroll")                                                     \
        for (int fr = 0; fr < 4; fr++)                                        \
            _Pragma("unroll")                                                 \
            for (int fc = 0; fc < 2; fc++)                                    \
                acc[g][fr][fc] = __builtin_amdgcn_mfma_f32_16x16x32_bf16(     \
                    af[fr][s], bfv[fc][s], acc[g][fr][fc], 0, 0, 0);          \
    __builtin_amdgcn_s_setprio(0);

template<bool BF16OUT>
__global__ __launch_bounds__(512, 2) void gemm8p(const unsigned short* __restrict__ A,
                                                 const unsigned short* __restrict__ B,
                                                 void* __restrict__ C0,
                                                 void* __restrict__ C1,
                                                 int N, int Kfull, int Ks,
                                                 int gx, int nwg1) {
    __shared__ unsigned short lds[2][2][2][8192];   // [tile-parity][op][half][128*64]
    const int tid = threadIdx.x;
    const int w = tid >> 6, lane = tid & 63;
    const int quad = lane >> 4, l16 = lane & 15;
    const int rx7 = l16 & 7;

    // bijective XCD swizzle (m204 form)
    const int nwg = gridDim.x;
    const int id = blockIdx.x;
    const int q8 = nwg >> 3, r8 = nwg & 7;
    const int xcd = id & 7, idx = id >> 3;
    const int wg = (xcd < r8 ? xcd * (q8 + 1) : r8 * (q8 + 1) + (xcd - r8) * q8) + idx;
    const int sid = wg / nwg1;
    const int wgl = wg % nwg1;
    const int m0 = (wgl / gx) * 256, n0 = (wgl % gx) * 256;
    const int kbase = sid * Ks;
    void* Cout = sid ? C1 : C0;

    const size_t a0r = (size_t)m0 * Kfull;
    const size_t a1r = (size_t)(m0 + 128) * Kfull;
    const size_t b0r = (size_t)n0 * Kfull;
    const size_t b1r = (size_t)(n0 + 128) * Kfull;

    f32x4 acc[4][4][2];
#pragma unroll
    for (int g = 0; g < 4; g++)
#pragma unroll
        for (int i = 0; i < 4; i++)
#pragma unroll
            for (int j = 0; j < 2; j++) acc[g][i][j] = (f32x4){0.f, 0.f, 0.f, 0.f};

    const int NT = Ks >> 6;            // K-tiles in this split (even; >= 4)
    // prologue: tile0 full (buf0) + tile1 A0,B0,A1 (buf1) = 7 halves
    stage_half(A, &lds[0][0][0][0], w, lane, a0r, Kfull, kbase);
    stage_half(B, &lds[0][1][0][0], w, lane, b0r, Kfull, kbase);
    stage_half(A, &lds[0][0][1][0], w, lane, a1r, Kfull, kbase);
    stage_half(B, &lds[0][1][1][0], w, lane, b1r, Kfull, kbase);
    stage_half(A, &lds[1][0][0][0], w, lane, a0r, Kfull, kbase + 64);
    stage_half(B, &lds[1][1][0][0], w, lane, b0r, Kfull, kbase + 64);
    stage_half(A, &lds[1][0][1][0], w, lane, a1r, Kfull, kbase + 64);
    WAITV(6); BARRIER;

    short8 af0[4][2], af1[4][2], bf0[2][2], bf1[2][2];
    for (int p = 0; p < (NT >> 1) - 1; p++) {
        const int kb1 = kbase + (2 * p + 1) * 64;   // odd tile of THIS pair (its B1)
        const int ka2 = kbase + (2 * p + 2) * 64;   // next even tile
        const int kb2 = kbase + (2 * p + 3) * 64;   // next odd tile
        // ph0: quadrant (A0,B0) of even tile
        READ_A(af0, 0, 0); READ_B(bf0, 0, 0);
        stage_half(B, &lds[1][1][1][0], w, lane, b1r, Kfull, kb1);
        BARRIER; MFMA16(0, af0, bf0); LGKM0; BARRIER;
        // ph1: (A1,B0)
        READ_A(af1, 0, 1);
        stage_half(A, &lds[0][0][0][0], w, lane, a0r, Kfull, ka2);
        BARRIER; MFMA16(1, af1, bf0); LGKM0; BARRIER;
        // ph2: (A0,B1)
        READ_B(bf1, 0, 1);
        stage_half(B, &lds[0][1][0][0], w, lane, b0r, Kfull, ka2);
        BARRIER; MFMA16(2, af0, bf1); LGKM0; BARRIER;
        // ph3: (A1,B1); drain odd tile of this pair (vmcnt 14->6)
        stage_half(A, &lds[0][0][1][0], w, lane, a1r, Kfull, ka2);
        WAITV(6); BARRIER; MFMA16(3, af1, bf1); LGKM0; BARRIER;
        // ph4: (A0,B0) of odd tile
        READ_A(af0, 1, 0); READ_B(bf0, 1, 0);
        stage_half(B, &lds[0][1][1][0], w, lane, b1r, Kfull, ka2);
        BARRIER; MFMA16(0, af0, bf0); LGKM0; BARRIER;
        // ph5: (A1,B0)
        READ_A(af1, 1, 1);
        stage_half(A, &lds[1][0][0][0], w, lane, a0r, Kfull, kb2);
        BARRIER; MFMA16(1, af1, bf0); LGKM0; BARRIER;
        // ph6: (A0,B1)
        READ_B(bf1, 1, 1);
        stage_half(B, &lds[1][1][0][0], w, lane, b0r, Kfull, kb2);
        BARRIER; MFMA16(2, af0, bf1); LGKM0; BARRIER;
        // ph7: (A1,B1); drain next even tile
        stage_half(A, &lds[1][0][1][0], w, lane, a1r, Kfull, kb2);
        WAITV(6); BARRIER; MFMA16(3, af1, bf1); LGKM0; BARRIER;
    }
    // epilogue pair: tiles NT-2 (buf0, fully landed), NT-1 (buf1; B1 staged here)
    READ_A(af0, 0, 0); READ_B(bf0, 0, 0);
    stage_half(B, &lds[1][1][1][0], w, lane, b1r, Kfull, kbase + (NT - 1) * 64);
    MFMA16(0, af0, bf0);
    READ_A(af1, 0, 1);
    MFMA16(1, af1, bf0);
    READ_B(bf1, 0, 1);
    MFMA16(2, af0, bf1);
    MFMA16(3, af1, bf1);
    WAITV(0); LGKM0; BARRIER;
    READ_A(af0, 1, 0); READ_B(bf0, 1, 0);
    MFMA16(0, af0, bf0);
    READ_A(af1, 1, 1);
    MFMA16(1, af1, bf0);
    READ_B(bf1, 1, 1);
    MFMA16(2, af0, bf1);
    MFMA16(3, af1, bf1);

    // C write
#pragma unroll
    for (int g = 0; g < 4; g++) {
        const int qm = g & 1, qn = g >> 1;
        const int mb = m0 + qm * 128 + (w & 1) * 64;
        const int nb2 = n0 + qn * 128 + (w >> 1) * 32;
#pragma unroll
        for (int fr = 0; fr < 4; fr++)
#pragma unroll
            for (int fc = 0; fc < 2; fc++) {
                const int n = nb2 + fc * 16 + l16;
#pragma unroll
                for (int rr = 0; rr < 4; rr++) {
                    const int m = mb + fr * 16 + quad * 4 + rr;
                    if (BF16OUT)
                        ((unsigned short*)Cout)[(size_t)m * N + n] = f2bf(acc[g][fr][fc][rr]);
                    else
                        ((float*)Cout)[(size_t)m * N + n] = acc[g][fr][fc][rr];
                }
            }
    }
}

// ---------------------------------------------------------------------------
// Skinny dt projection: BM=32, grid 256. Waves split K (256 each) with
// per-wave double-buffered global_load_lds (no barriers in K-loop); f32
// LDS reduce across waves, fused bias+sigmoid epilogue.
// ---------------------------------------------------------------------------
__global__ __launch_bounds__(256) void dtproj_mfma(const unsigned short* __restrict__ A,
                                                   const unsigned short* __restrict__ W,
                                                   const float* __restrict__ bias,
                                                   float* __restrict__ dtb,
                                                   int K) {
    __shared__ unsigned short As[4][2][32 * 32];
    __shared__ unsigned short Ws[4][2][32 * 32];
    __shared__ float red[4][32][32];
    const int tid = threadIdx.x;
    const int w = tid >> 6, lane = tid & 63;
    const int quad = lane >> 4, l16 = lane & 15;
    const int m0 = blockIdx.x * 32;
    const int kbeg = w * (1024 / 4);

    f32x4 acc[2][2];
#pragma unroll
    for (int i = 0; i < 2; i++)
#pragma unroll
        for (int j = 0; j < 2; j++) acc[i][j] = (f32x4){0.f, 0.f, 0.f, 0.f};

#define DTSTAGE(buf, kt)                                                      \
    _Pragma("unroll")                                                         \
    for (int u = 0; u < 2; u++) {                                             \
        const int f = u * 64 + lane;                                          \
        const int row = f >> 2, ke = (f & 3) * 8;                             \
        gload16(A + (size_t)(m0 + row) * K + (kt) + ke,                       \
                (char*)&As[w][buf][0] + f * 16);                              \
        gload16(W + (size_t)row * K + (kt) + ke,                              \
                (char*)&Ws[w][buf][0] + f * 16);                              \
    }

    DTSTAGE(0, kbeg);
    int buf = 0;
    for (int it = 0; it < 8; it++) {
        if (it < 7) { DTSTAGE(buf ^ 1, kbeg + (it + 1) * 32); WAITV(4); }
        else        { WAITV(0); }
        short8 af[2], bfr[2];
#pragma unroll
        for (int i = 0; i < 2; i++)
            af[i] = *(const short8*)((const char*)&As[w][buf][0] + (i * 16 + l16) * 64 + quad * 16);
#pragma unroll
        for (int j = 0; j < 2; j++)
            bfr[j] = *(const short8*)((const char*)&Ws[w][buf][0] + (j * 16 + l16) * 64 + quad * 16);
#pragma unroll
        for (int i = 0; i < 2; i++)
#pragma unroll
            for (int j = 0; j < 2; j++)
                acc[i][j] = __builtin_amdgcn_mfma_f32_16x16x32_bf16(
                    af[i], bfr[j], acc[i][j], 0, 0, 0);
        buf ^= 1;
    }
#pragma unroll
    for (int i = 0; i < 2; i++)
#pragma unroll
        for (int j = 0; j < 2; j++)
#pragma unroll
            for (int r = 0; r < 4; r++)
                red[w][i * 16 + quad * 4 + r][j * 16 + l16] = acc[i][j][r];
    __syncthreads();
#pragma unroll
    for (int e = 0; e < 4; e++) {
        const int o = tid + e * 256;
        const int m = o >> 5, hh = o & 31;
        const float v = red[0][m][hh] + red[1][m][hh] + red[2][m][hh] + red[3][m][hh];
        dtb[(size_t)m0 * NHEADS + o] = 0.001f + 0.099f * sigm_(v + bias[hh]);
    }
}

// ---------------------------------------------------------------------------
// Depthwise causal conv (K=4) + bias + SiLU, bf16 in/out.
// ---------------------------------------------------------------------------
__global__ __launch_bounds__(256) void conv_silu_w(const unsigned short* __restrict__ xbc,
                                                   const float* __restrict__ cw,
                                                   const float* __restrict__ cb,
                                                   unsigned short* __restrict__ xssm,
                                                   unsigned short* __restrict__ Bb,
                                                   unsigned short* __restrict__ Cb) {
    const int idx = blockIdx.x * 256 + threadIdx.x;   // < (ROWS/4)*CGRP
    const int g = idx % CGRP;
    const int rowblk = idx / CGRP;
    const long row0 = (long)rowblk * 4;
    const int lbase = (int)(row0 & (LEN - 1));        // position within sequence
    const int j0 = g * 8;

    float4 wv[8];
    float cbv[8];
#pragma unroll
    for (int e = 0; e < 8; e++) {
        wv[e] = *(const float4*)(cw + (size_t)(j0 + e) * 4);
        cbv[e] = cb[j0 + e];
    }

    short8 win[4];
    const short8 zero8 = (short8){0, 0, 0, 0, 0, 0, 0, 0};
#pragma unroll
    for (int t = 0; t < 3; t++) {
        const int lr = lbase - 3 + t;
        win[t] = (lr >= 0) ? *(const short8*)(xbc + (row0 - 3 + t) * CONVDIM + j0)
                           : zero8;
    }
#pragma unroll
    for (int i = 0; i < 4; i++) {
        win[3] = *(const short8*)(xbc + (row0 + i) * CONVDIM + j0);
        short8 o;
#pragma unroll
        for (int e = 0; e < 8; e++) {
            float acc = cbv[e];
            acc += bf2f((unsigned short)win[0][e]) * wv[e].x;
            acc += bf2f((unsigned short)win[1][e]) * wv[e].y;
            acc += bf2f((unsigned short)win[2][e]) * wv[e].z;
            acc += bf2f((unsigned short)win[3][e]) * wv[e].w;
            o[e] = (short)f2bf(silu_(acc));
        }
        const long row = row0 + i;
        if (j0 < DINNER)
            *(short8*)(xssm + row * DINNER + j0) = o;
        else if (j0 < DINNER + DSTATE)
            *(short8*)(Bb + row * DSTATE + (j0 - DINNER)) = o;
        else
            *(short8*)(Cb + row * DSTATE + (j0 - DINNER - DSTATE)) = o;
        win[0] = win[1]; win[1] = win[2]; win[2] = win[3];
    }
}

__global__ __launch_bounds__(64) void acum_kernel(const float* __restrict__ dtb,
                                                  const float* __restrict__ A_log,
                                                  float* __restrict__ Acum) {
    const int c = blockIdx.x, h = blockIdx.y, b = blockIdx.z;
    const int q = threadIdx.x;
    const float Av = -expf(A_log[h]);
    float v = dtb[((size_t)b * LEN + c * QC + q) * NHEADS + h] * Av;
#pragma unroll
    for (int off = 1; off < 64; off <<= 1) {
        const float n = __shfl_up(v, off, 64);
        if (q >= off) v += n;
    }
    Acum[(((size_t)b * NHEADS + h) * NCHUNK + c) * QC + q] = v;
}

// ---------------------------------------------------------------------------
// MFMA chunk kernel (PT tiles XOR-swizzled).
// ---------------------------------------------------------------------------
__global__ __launch_bounds__(256) void chunk_mfma(const unsigned short* __restrict__ xssm,
                                                  const unsigned short* __restrict__ Bb,
                                                  const unsigned short* __restrict__ Cb,
                                                  const float* __restrict__ dtb,
                                                  const float* __restrict__ Acum,
                                                  const float* __restrict__ Dskip,
                                                  unsigned short* __restrict__ Y,
                                                  unsigned short* __restrict__ states) {
    const int c = blockIdx.x, h = blockIdx.y, b = blockIdx.z;
    const int tid = threadIdx.x;
    const int wave = tid >> 6, lane = tid & 63;
    const int quad = lane >> 4, l16 = lane & 15;

    __shared__ __attribute__((aligned(16))) unsigned short Bsh[8704];
    __shared__ __attribute__((aligned(16))) unsigned short Csh[9216];
    __shared__ __attribute__((aligned(16))) unsigned short xTs[4608];
    __shared__ float ac[QC], dts[QC], decs[QC];

    const size_t rowbase = (size_t)b * LEN + c * QC;
    if (tid < QC) {
        ac[tid]  = Acum[(((size_t)b * NHEADS + h) * NCHUNK + c) * QC + tid];
        dts[tid] = dtb[(rowbase + tid) * NHEADS + h];
    }
#pragma unroll
    for (int u = 0; u < 4; u++) {
        const int vi = u * 256 + tid;
        const int s = vi >> 4, n0 = (vi & 15) * 8;
        *(short8*)&Bsh[s * PB + n0] = *(const short8*)(Bb + (rowbase + s) * DSTATE + n0);
        *(short8*)&Csh[s * PB + n0] = *(const short8*)(Cb + (rowbase + s) * DSTATE + n0);
    }
#pragma unroll
    for (int u = 0; u < 2; u++) {
        const int vi = u * 256 + tid;
        const int q = vi >> 3, p0 = (vi & 7) * 8;
        const short8 v = *(const short8*)(xssm + (rowbase + q) * DINNER + h * HDIM + p0);
#pragma unroll
        for (int j = 0; j < 8; j++) {
            const int p = p0 + j;
            xTs[p * PT + swzcol(p, q)] = (unsigned short)v[j];
        }
    }
    __syncthreads();
    if (tid < QC) decs[tid] = expf(ac[QC - 1] - ac[tid]) * dts[tid];

    // Phase 1: S = C . B^T   (PB natural layout)
    f32x4 S[4];
#pragma unroll
    for (int j = 0; j < 4; j++) S[j] = (f32x4){0.f, 0.f, 0.f, 0.f};
    const int qa = wave * 16 + l16;
#pragma unroll
    for (int ks = 0; ks < 4; ks++) {
        const short8 a = *(const short8*)&Csh[qa * PB + ks * 32 + quad * 8];
#pragma unroll
        for (int j = 0; j < 4; j++) {
            const short8 bb = *(const short8*)&Bsh[(j * 16 + l16) * PB + ks * 32 + quad * 8];
            S[j] = __builtin_amdgcn_mfma_f32_16x16x32_bf16(a, bb, S[j], 0, 0, 0);
        }
    }
    unsigned short slv[4][4];
#pragma unroll
    for (int j = 0; j < 4; j++)
#pragma unroll
        for (int r = 0; r < 4; r++) {
            const int q = wave * 16 + quad * 4 + r, s = j * 16 + l16;
            const float v = (s <= q) ? S[j][r] * expf(ac[q] - ac[s]) * dts[s] : 0.f;
            slv[j][r] = f2bf(v);
        }
    __syncthreads();

    // B'[n][s] = B[s][n]*decs[s], written swizzled into Csh (PT pitch).
    {
        const int sin = lane & 7;
        const int ng  = lane >> 3;
#pragma unroll
        for (int so = 0; so < 2; so++) {
            const int s = (wave * 2 + so) * 8 + sin;
            const float d = decs[s];
            const int cbk = s >> 3;
#pragma unroll
            for (int nh = 0; nh < 2; nh++) {
                const int noct = ng + 8 * nh;
                const int colphys = (((cbk ^ noct) & 7) << 3) | (s & 7);
#pragma unroll
                for (int j = 0; j < 8; j++) {
                    const int n = noct * 8 + ((j + sin) & 7);
                    Csh[n * PT + colphys] = f2bf(bf2f(Bsh[s * PB + n]) * d);
                }
            }
        }
    }
    __syncthreads();

#pragma unroll
    for (int j = 0; j < 4; j++)
#pragma unroll
        for (int r = 0; r < 4; r++) {
            const int row = wave * 16 + quad * 4 + r;
            const int col = j * 16 + l16;
            Bsh[row * PT + swzcol(row, col)] = slv[j][r];
        }
    __syncthreads();

    // Phase 2: Yd = SL . x
    f32x4 yd[4];
#pragma unroll
    for (int j = 0; j < 4; j++) yd[j] = (f32x4){0.f, 0.f, 0.f, 0.f};
#pragma unroll
    for (int ks = 0; ks < 2; ks++) {
        const int blk = ks * 4 + quad;
        const short8 a = *(const short8*)&Bsh[qa * PT + swzblk(qa, blk)];
#pragma unroll
        for (int j = 0; j < 4; j++) {
            const int row = j * 16 + l16;
            const short8 xb = *(const short8*)&xTs[row * PT + swzblk(row, blk)];
            yd[j] = __builtin_amdgcn_mfma_f32_16x16x32_bf16(a, xb, yd[j], 0, 0, 0);
        }
    }
    const float Dh = Dskip[h];
#pragma unroll
    for (int j = 0; j < 4; j++)
#pragma unroll
        for (int r = 0; r < 4; r++) {
            const int q = wave * 16 + quad * 4 + r, p = j * 16 + l16;
            const float v = yd[j][r] + Dh * bf2f(xTs[p * PT + swzcol(p, q)]);
            Y[(rowbase + q) * DINNER + h * HDIM + p] = f2bf(v);
        }

    // Phase 3: states = xT . B'
    f32x4 st[8];
#pragma unroll
    for (int j = 0; j < 8; j++) st[j] = (f32x4){0.f, 0.f, 0.f, 0.f};
#pragma unroll
    for (int ks = 0; ks < 2; ks++) {
        const int blk = ks * 4 + quad;
        const short8 a = *(const short8*)&xTs[qa * PT + swzblk(qa, blk)];
#pragma unroll
        for (int j = 0; j < 8; j++) {
            const int row = j * 16 + l16;
            const short8 bb = *(const short8*)&Csh[row * PT + swzblk(row, blk)];
            st[j] = __builtin_amdgcn_mfma_f32_16x16x32_bf16(a, bb, st[j], 0, 0, 0);
        }
    }
    const size_t sbase = (((size_t)b * NHEADS + h) * NCHUNK + c) * SDIM;
#pragma unroll
    for (int j = 0; j < 8; j++)
#pragma unroll
        for (int r = 0; r < 4; r++) {
            const int p = wave * 16 + quad * 4 + r, n = j * 16 + l16;
            states[sbase + (size_t)p * DSTATE + n] = f2bf(st[j][r]);
        }
}

// Sequential inter-chunk scan (bf16 storage, f32 carry)
__global__ __launch_bounds__(256) void scan_kernel(unsigned short* __restrict__ states,
                                                   const float* __restrict__ Acum) {
    __shared__ float dec[NCHUNK];
    const int bh = blockIdx.y;
    const int pn = blockIdx.x * 256 + threadIdx.x;
    if (threadIdx.x < NCHUNK)
        dec[threadIdx.x] = expf(Acum[((size_t)bh * NCHUNK + threadIdx.x) * QC + (QC - 1)]);
    __syncthreads();
    float carry = 0.f;
    const size_t base = (size_t)bh * NCHUNK * SDIM + pn;
    for (int c = 0; c < NCHUNK; c++) {
        const size_t idx = base + (size_t)c * SDIM;
        const float s = bf2f(states[idx]);
        states[idx] = f2bf(carry);
        carry = dec[c] * carry + s;
    }
}

// MFMA yo kernel: Yo[q][p] = eq[q] * sum_n C[q][n]*prev[p][n];  Y += Yo (bf16)
__global__ __launch_bounds__(256) void yo_mfma(const unsigned short* __restrict__ Cb,
                                               const unsigned short* __restrict__ prevs,
                                               const float* __restrict__ Acum,
                                               unsigned short* __restrict__ Y) {
    const int c = blockIdx.x, h = blockIdx.y, b = blockIdx.z;
    const int tid = threadIdx.x;
    const int wave = tid >> 6, lane = tid & 63;
    const int quad = lane >> 4, l16 = lane & 15;
    __shared__ __attribute__((aligned(16))) unsigned short Csh[8704];
    __shared__ __attribute__((aligned(16))) unsigned short Psh[8704];
    __shared__ float eq[QC];
    const size_t rowbase = (size_t)b * LEN + c * QC;
    const size_t pbase = (((size_t)b * NHEADS + h) * NCHUNK + c) * SDIM;
    if (tid < QC)
        eq[tid] = expf(Acum[(((size_t)b * NHEADS + h) * NCHUNK + c) * QC + tid]);
#pragma unroll
    for (int u = 0; u < 4; u++) {
        const int vi = u * 256 + tid;
        const int r = vi >> 4, n0 = (vi & 15) * 8;
        *(short8*)&Csh[r * PB + n0] = *(const short8*)(Cb + (rowbase + r) * DSTATE + n0);
        *(short8*)&Psh[r * PB + n0] = *(const short8*)(prevs + pbase + (size_t)r * DSTATE + n0);
    }
    __syncthreads();

    f32x4 acc[4];
#pragma unroll
    for (int j = 0; j < 4; j++) acc[j] = (f32x4){0.f, 0.f, 0.f, 0.f};
    const int qa = wave * 16 + l16;
#pragma unroll
    for (int ks = 0; ks < 4; ks++) {
        const short8 a = *(const short8*)&Csh[qa * PB + ks * 32 + quad * 8];
#pragma unroll
        for (int j = 0; j < 4; j++) {
            const short8 bb = *(const short8*)&Psh[(j * 16 + l16) * PB + ks * 32 + quad * 8];
            acc[j] = __builtin_amdgcn_mfma_f32_16x16x32_bf16(a, bb, acc[j], 0, 0, 0);
        }
    }
#pragma unroll
    for (int j = 0; j < 4; j++)
#pragma unroll
        for (int r = 0; r < 4; r++) {
            const int q = wave * 16 + quad * 4 + r, p = j * 16 + l16;
            const size_t off = (rowbase + q) * DINNER + h * HDIM + p;
            Y[off] = f2bf(bf2f(Y[off]) + eq[q] * acc[j][r]);
        }
}

// y = Y * silu(z); RMS-norm; write bf16 for GEMM2  (all bf16 I/O)
__global__ __launch_bounds__(256) void gate_rms(const unsigned short* __restrict__ Y,
                                                const unsigned short* __restrict__ zbf,
                                                const float* __restrict__ nw,
                                                unsigned short* __restrict__ ybf) {
    const int r = blockIdx.x, tid = threadIdx.x;
    float4 yv[2];
    float ss = 0.f;
#pragma unroll
    for (int u = 0; u < 2; u++) {
        const int col = u * 1024 + tid * 4;
        const ushort4 y4 = *(const ushort4*)(Y + (size_t)r * DINNER + col);
        const ushort4 z4 = *(const ushort4*)(zbf + (size_t)r * DINNER + col);
        float4 y;
        y.x = bf2f(y4.x) * silu_(bf2f(z4.x)); y.y = bf2f(y4.y) * silu_(bf2f(z4.y));
        y.z = bf2f(y4.z) * silu_(bf2f(z4.z)); y.w = bf2f(y4.w) * silu_(bf2f(z4.w));
        yv[u] = y;
        ss += y.x * y.x + y.y * y.y + y.z * y.z + y.w * y.w;
    }
#pragma unroll
    for (int off = 32; off; off >>= 1) ss += __shfl_xor(ss, off, 64);
    __shared__ float red[4];
    if ((tid & 63) == 0) red[tid >> 6] = ss;
    __syncthreads();
    ss = red[0] + red[1] + red[2] + red[3];
    const float scale = rsqrtf(ss / (float)DINNER + 1e-5f);
#pragma unroll
    for (int u = 0; u < 2; u++) {
        const int col = u * 1024 + tid * 4;
        const float4 w4 = *(const float4*)(nw + col);
        ushort4 o;
        o.x = f2bf(yv[u].x * scale * w4.x); o.y = f2bf(yv[u].y * scale * w4.y);
        o.z = f2bf(yv[u].z * scale * w4.z); o.w = f2bf(yv[u].w * scale * w4.w);
        *(ushort4*)(ybf + (size_t)r * DINNER + col) = o;
    }
}

// LayerNorm over D + residual. outb + part are summed (split-K partials).
__global__ __launch_bounds__(256) void ln_res(const float* __restrict__ outb,
                                              const float* __restrict__ part,
                                              const float* __restrict__ x,
                                              const float* __restrict__ lw,
                                              const float* __restrict__ lb,
                                              float* __restrict__ out) {
    const int r = blockIdx.x, tid = threadIdx.x;
    const int col = tid * 4;
    float4 v = *(const float4*)(outb + (size_t)r * DMODEL + col);
    const float4 pv = *(const float4*)(part + (size_t)r * DMODEL + col);
    v.x += pv.x; v.y += pv.y; v.z += pv.z; v.w += pv.w;
    float s = v.x + v.y + v.z + v.w;
    float s2 = v.x * v.x + v.y * v.y + v.z * v.z + v.w * v.w;
#pragma unroll
    for (int off = 32; off; off >>= 1) {
        s += __shfl_xor(s, off, 64);
        s2 += __shfl_xor(s2, off, 64);
    }
    __shared__ float rs[4], rs2[4];
    if ((tid & 63) == 0) { rs[tid >> 6] = s; rs2[tid >> 6] = s2; }
    __syncthreads();
    s = rs[0] + rs[1] + rs[2] + rs[3];
    s2 = rs2[0] + rs2[1] + rs2[2] + rs2[3];
    const float mu = s / (float)DMODEL;
    const float var = s2 / (float)DMODEL - mu * mu;
    const float inv = rsqrtf(var + 1e-5f);
    const float4 xw = *(const float4*)(x + (size_t)r * DMODEL + col);
    const float4 w4 = *(const float4*)(lw + col);
    const float4 b4 = *(const float4*)(lb + col);
    float4 o;
    o.x = xw.x + (v.x - mu) * inv * w4.x + b4.x;
    o.y = xw.y + (v.y - mu) * inv * w4.y + b4.y;
    o.z = xw.z + (v.z - mu) * inv * w4.z + b4.z;
    o.w = xw.w + (v.w - mu) * inv * w4.w + b4.w;
    *(float4*)(out + (size_t)r * DMODEL + col) = o;
}

extern "C" void kernel_launch(void* const* d_in, const int* in_sizes, int n_in,
                              void* d_out, int out_size, void* d_ws, size_t ws_size,
                              hipStream_t stream) {
    const float* x          = (const float*)d_in[0];
    const float* in_proj_w  = (const float*)d_in[1];
    const float* conv_w     = (const float*)d_in[2];
    const float* conv_b     = (const float*)d_in[3];
    const float* dt_bias    = (const float*)d_in[4];
    const float* A_log      = (const float*)d_in[5];
    const float* D_skip     = (const float*)d_in[6];
    const float* norm_w     = (const float*)d_in[7];
    const float* out_proj_w = (const float*)d_in[8];
    const float* ln_w       = (const float*)d_in[9];
    const float* ln_b       = (const float*)d_in[10];
    float* out = (float*)d_out;
    float* ws = (float*)d_ws;

    // Workspace layout (float units). ~243 MB.
    size_t off = 0;
    unsigned short* zbf     = (unsigned short*)(ws + off); off += (size_t)ROWS * DINNER / 2;
    unsigned short* xssm_bf = (unsigned short*)(ws + off); off += (size_t)ROWS * DINNER / 2;
    unsigned short* uni     = (unsigned short*)(ws + off); off += (size_t)ROWS * CONVDIM / 2;
    unsigned short* Bb_bf   = (unsigned short*)(ws + off); off += (size_t)ROWS * DSTATE / 2;
    unsigned short* Cb_bf   = (unsigned short*)(ws + off); off += (size_t)ROWS * DSTATE / 2;
    float* dtb   = ws + off; off += (size_t)ROWS * NHEADS;
    float* Acum  = ws + off; off += (size_t)BSZ * NHEADS * NCHUNK * QC;
    unsigned short* x_bf  = (unsigned short*)(ws + off); off += (size_t)ROWS * DMODEL / 2;
    unsigned short* wi_bf = (unsigned short*)(ws + off); off += (size_t)4384 * DMODEL / 2;
    unsigned short* wo_bf = (unsigned short*)(ws + off); off += (size_t)DMODEL * DINNER / 2;
    unsigned short* states = (unsigned short*)(ws + off); off += (size_t)BSZ * NHEADS * NCHUNK * SDIM / 2;
    float* part = ws + off; off += (size_t)ROWS * DMODEL;   // split-K partial (f32)
    const size_t need_bytes = off * sizeof(float);
    if (ws_size < need_bytes) return;   // fail cleanly instead of faulting

    unsigned short* xbc_bf = uni;        // dies after conv
    unsigned short* Ybf    = uni;        // chunk output overlays dead xbc
    unsigned short* ybf    = xssm_bf;    // gate output overlays dead xssm

    // Casts (one fused dispatch)
    {
        const int n0 = ROWS * DMODEL / 4, n1 = 4384 * DMODEL / 4, n2 = DMODEL * DINNER / 4;
        cast3<<<(n0 + n1 + n2 + 255) / 256, 256, 0, stream>>>(
            x, x_bf, n0, in_proj_w, wi_bf, n1, out_proj_w, wo_bf, n2);
    }

    // In-projection (256^2 8-phase bf16 MFMA): z, xBC; dt via skinny MFMA
    gemm8p<true><<<(ROWS / 256) * (DINNER / 256), 512, 0, stream>>>(
        x_bf, wi_bf, zbf, nullptr, DINNER, DMODEL, DMODEL,
        DINNER / 256, (ROWS / 256) * (DINNER / 256));
    gemm8p<true><<<(ROWS / 256) * (CONVDIM / 256), 512, 0, stream>>>(
        x_bf, wi_bf + (size_t)DINNER * DMODEL, xbc_bf, nullptr, CONVDIM, DMODEL, DMODEL,
        CONVDIM / 256, (ROWS / 256) * (CONVDIM / 256));
    dtproj_mfma<<<ROWS / 32, 256, 0, stream>>>(
        x_bf, wi_bf + (size_t)(DINNER + CONVDIM) * DMODEL, dt_bias, dtb, DMODEL);

    conv_silu_w<<<(ROWS / 4) * CGRP / 256, 256, 0, stream>>>(
        xbc_bf, conv_w, conv_b, xssm_bf, Bb_bf, Cb_bf);
    acum_kernel<<<dim3(NCHUNK, NHEADS, BSZ), 64, 0, stream>>>(dtb, A_log, Acum);
    chunk_mfma<<<dim3(NCHUNK, NHEADS, BSZ), 256, 0, stream>>>(
        xssm_bf, Bb_bf, Cb_bf, dtb, Acum, D_skip, Ybf, states);
    scan_kernel<<<dim3(SDIM / 256, BSZ * NHEADS), 256, 0, stream>>>(states, Acum);
    yo_mfma<<<dim3(NCHUNK, NHEADS, BSZ), 256, 0, stream>>>(Cb_bf, states, Acum, Ybf);
    gate_rms<<<ROWS, 256, 0, stream>>>(Ybf, zbf, norm_w, ybf);

    // Out-projection: split-K=2 (K=2048 -> 2x1024), grid 256, one dispatch.
    gemm8p<false><<<2 * (ROWS / 256) * (DMODEL / 256), 512, 0, stream>>>(
        ybf, wo_bf, out, part, DMODEL, DINNER, DINNER / 2,
        DMODEL / 256, (ROWS / 256) * (DMODEL / 256));
    ln_res<<<ROWS, 256, 0, stream>>>(out, part, x, ln_w, ln_b, out);
}